// Round 10
// baseline (396.331 us; speedup 1.0000x reference)
//
#include <hip/hip_runtime.h>
#include <hip/hip_bf16.h>
#include <stdint.h>

// GNN_758: stacked RelGraphConv x2.  N=50000, E=1.6M, D=128, R=20.
// agg[dst] = sum_r (sum_{e in rel r -> dst} h[src]) @ W[r]; self-loop = rel 20.
// R17: layer kernel = R15 verbatim (proven, 124us; f16 walk + f16 MFMA).
// R16's ds_pk_add_f16 phase-1 failed refcheck (absmax 10.7 ~ one misrouted
// cell; instruction semantics unverifiable) -> abandoned. Salvaged R16's prep:
// tile-bucket counting sort with coalesced cnt[blk][bin] rows + per-bin
// colscan + ONE-block scan (replaces the 1.5M-word scanA/B/C chain and the
// uncoalesced (bin,blk) writes), then R15's tile_sort unchanged (payload
// keeps full 5-bit rel so cofs/es format is byte-identical to R15).

#define NN 50000
#define NE 1600000
#define DIM 128
#define NREL 20
#define NRELP 21
#define TILE 16
#define NTILE (NN / TILE)          // 3125 = tile bins
#define CELLS (NN * NREL)          // dst*20 + r
#define CHB 256                    // chunk blocks for count/scatter
#define CHE (NE / CHB)             // 6250 edges per chunk block
#define SPK_CAP 1024               // staged srcs per block (mean 512, sd ~23)
#define PACKED_ELEMS (2 * NRELP * 4 * 8 * 64 * 8)    // 688128

typedef __attribute__((ext_vector_type(8))) short short8;
typedef __attribute__((ext_vector_type(8))) _Float16 half8;
typedef __attribute__((ext_vector_type(4))) float f32x4;

__device__ __forceinline__ unsigned short f32_to_f16_raw(float f) {
  union { _Float16 h; unsigned short u; } c;
  c.h = (_Float16)f;               // v_cvt_f16_f32 (RNE)
  return c.u;
}

// ---------------- fp32 -> f16 (x4), nontemporal stores ----------------
__global__ void cvt_f16_kernel(const float* __restrict__ in,
                               unsigned short* __restrict__ out, int n4) {
  int i = blockIdx.x * 256 + threadIdx.x;
  if (i < n4) {
    float4 f = ((const float4*)in)[i];
    unsigned long long p =
        (unsigned long long)f32_to_f16_raw(f.x)
      | ((unsigned long long)f32_to_f16_raw(f.y) << 16)
      | ((unsigned long long)f32_to_f16_raw(f.z) << 32)
      | ((unsigned long long)f32_to_f16_raw(f.w) << 48);
    __builtin_nontemporal_store(p, (unsigned long long*)out + i);  // clean -> L3
  }
}

// ---------------- pack W (+loop_w as rel 20) into B-fragment order ----------------
// WP flat: ((((l*21 + r)*4 + ks)*8 + nc)*64 + lane)*8  (verified R0/R1), f16
__global__ void pack_w_kernel(const float* __restrict__ W,
                              const float* __restrict__ loop_w,
                              unsigned short* __restrict__ WP) {
  int idx = blockIdx.x * 256 + threadIdx.x;
  if (idx >= PACKED_ELEMS) return;
  int j = idx & 7;       int t = idx >> 3;
  int lane = t & 63;     t >>= 6;
  int nc = t & 7;        t >>= 3;
  int ks = t & 3;        t >>= 2;
  int r = t % NRELP;     int l = t / NRELP;
  int k = ks * 32 + (lane >> 4) * 8 + j;
  int n = nc * 16 + (lane & 15);
  float v = (r < NREL) ? W[(((size_t)l * NREL + r) * DIM + k) * DIM + n]
                       : loop_w[((size_t)l * DIM + k) * DIM + n];
  WP[idx] = f32_to_f16_raw(v);
}

// ---------------- tile counting sort, all global accesses coalesced ----------------
// bin = dst>>4 (3125 bins).  cnt layout: [blk][NTILE] rows (coalesced).
__global__ __launch_bounds__(256) void cnt_kernel(
    const int* __restrict__ dst, unsigned int* __restrict__ cnt) {
  __shared__ unsigned int h[NTILE];              // 12.5 KB
  for (int i = threadIdx.x; i < NTILE; i += 256) h[i] = 0u;
  __syncthreads();
  const int base = blockIdx.x * CHE;
  for (int i = base + threadIdx.x; i < base + CHE; i += 256)
    atomicAdd(&h[dst[i] >> 4], 1u);              // LDS atomic
  __syncthreads();
  unsigned int* row = cnt + (size_t)blockIdx.x * NTILE;
  for (int i = threadIdx.x; i < NTILE; i += 256) row[i] = h[i];
}

// per-bin exclusive prefix over blk (in place) + column totals.
__global__ __launch_bounds__(256) void colscan_kernel(
    unsigned int* __restrict__ cnt, unsigned int* __restrict__ csum) {
  int b = blockIdx.x * 256 + threadIdx.x;
  if (b >= NTILE) return;
  unsigned int run = 0;
  for (int blk = 0; blk < CHB; blk += 8) {       // CHB % 8 == 0
    unsigned int v[8];
#pragma unroll
    for (int i = 0; i < 8; ++i) v[i] = cnt[(size_t)(blk + i) * NTILE + b];
#pragma unroll
    for (int i = 0; i < 8; ++i) { cnt[(size_t)(blk + i) * NTILE + b] = run; run += v[i]; }
  }
  csum[b] = run;
}

// single-block exclusive scan of csum[NTILE] -> starts[NTILE+1] (sentinel=NE)
__global__ __launch_bounds__(1024) void scan1_kernel(
    const unsigned int* __restrict__ csum, unsigned int* __restrict__ starts) {
  __shared__ unsigned int buf[1024];
  const int t = threadIdx.x;
  const int base = t * 4;
  unsigned int v[4], p[4], s = 0;
#pragma unroll
  for (int j = 0; j < 4; ++j) {
    v[j] = (base + j < NTILE) ? csum[base + j] : 0u;
    p[j] = s; s += v[j];
  }
  buf[t] = s;
  __syncthreads();
  for (int d = 1; d < 1024; d <<= 1) {
    unsigned int a = (t >= d) ? buf[t - d] : 0u;
    __syncthreads();
    buf[t] += a;
    __syncthreads();
  }
  unsigned int excl = buf[t] - s;
#pragma unroll
  for (int j = 0; j < 4; ++j)
    if (base + j < NTILE) starts[base + j] = excl + p[j];
  if (t == 1023) starts[NTILE] = buf[1023];      // = NE
}

// scatter to tile-sorted position. payload = src | dd<<16 | rel<<20 (5 bits).
__global__ __launch_bounds__(256) void scatter_kernel(
    const int* __restrict__ src, const int* __restrict__ dst,
    const int* __restrict__ et, const unsigned int* __restrict__ starts,
    const unsigned int* __restrict__ cnt, unsigned int* __restrict__ ep) {
  __shared__ unsigned int cur[NTILE];            // 12.5 KB
  const unsigned int* row = cnt + (size_t)blockIdx.x * NTILE;
  for (int i = threadIdx.x; i < NTILE; i += 256)
    cur[i] = starts[i] + row[i];
  __syncthreads();
  const int base = blockIdx.x * CHE;
  for (int i = base + threadIdx.x; i < base + CHE; i += 256) {
    int d = dst[i];
    unsigned int pos = atomicAdd(&cur[d >> 4], 1u);   // LDS atomic
    ep[pos] = (unsigned int)src[i] | ((unsigned int)(d & 15) << 16)
            | ((unsigned int)et[i] << 20);
  }
}

// per-tile 320-bin sort -> cofs (dst*20+r layout) + es (u16 src). (= R15)
__global__ __launch_bounds__(512) void tile_sort_kernel(
    const unsigned int* __restrict__ ep, const unsigned int* __restrict__ starts,
    unsigned short* __restrict__ es, unsigned int* __restrict__ cofs) {
  __shared__ unsigned int hist[512];             // 320 bins, padded for scan
  const int t = threadIdx.x;
  const int tile = blockIdx.x;
  const unsigned int start = starts[tile];
  const unsigned int end = starts[tile + 1];
  const int cnt = (int)(end - start);
  hist[t] = 0u;
  __syncthreads();
  for (int i = t; i < cnt; i += 512) {
    unsigned int p = ep[start + i];
    atomicAdd(&hist[((p >> 16) & 15u) * 20u + (p >> 20)], 1u);
  }
  __syncthreads();
  unsigned int own = hist[t];
  for (int d = 1; d < 512; d <<= 1) {
    __syncthreads();
    unsigned int a = (t >= d) ? hist[t - d] : 0u;
    __syncthreads();
    hist[t] += a;
  }
  __syncthreads();
  unsigned int excl = hist[t] - own;     // exclusive prefix (own slot only)
  hist[t] = excl;                        // becomes rank cursor
  if (t < 320) cofs[(size_t)tile * 320 + t] = start + excl;
  if (tile == NTILE - 1 && t == 0) cofs[CELLS] = (unsigned int)NE;
  __syncthreads();
  for (int i = t; i < cnt; i += 512) {
    unsigned int p = ep[start + i];
    int sub = (int)(((p >> 16) & 15u) * 20u + (p >> 20));
    unsigned int rk = atomicAdd(&hist[sub], 1u);
    es[start + rk] = (unsigned short)(p & 0xffffu);
  }
}

// ---------------- fused RGCN layer (R15 verbatim) ----------------
// 3125 blocks x 512 threads (8 waves). LDS ~23.3KB -> 4 blocks/CU (wave cap).
__global__ __launch_bounds__(512, 8) void rgcn_layer_kernel(
    const unsigned short* __restrict__ hb,    // [N,128] f16
    const unsigned short* __restrict__ WP,    // packed weights, f16
    const float* __restrict__ bias,           // [128] this layer
    int layer,
    const unsigned int* __restrict__ cofs,    // [CELLS+1] cell offsets
    const unsigned short* __restrict__ es,    // [E] srcs, cell-sorted
    float* __restrict__ outf,                 // fp32 out (layer 1) or null
    unsigned short* __restrict__ outb)        // f16 out (layer 0) or null
{
  // Sb: [16 dst rows][5 rl slots * 16 slot16], slot16 = 8 f16 (16B),
  // slot index ^= (row & 15) -> conflict-free writes and reads (verified R8).
  __shared__ half8 Sb8[TILE * 80];           // 20480 B
  __shared__ unsigned int cofs_l[321];       // 1284 B
  __shared__ unsigned short spk[SPK_CAP];    // 2048 B

  const int tid  = threadIdx.x;
  const int lane = tid & 63;
  const int w    = tid >> 6;        // wave 0..7
  const int quad = lane >> 4;
  const int m    = lane & 15;
  const int mh8  = m * 8;
  const int half = w >> 2;          // 0: rl{0,1}  1: rl{2,3,4}  (wave-uniform)
  const int g    = (w & 3) * 4 + quad;   // owned dst_local 0..15
  const int dst_base = blockIdx.x * TILE;

  for (int i = tid; i < 321; i += 512) cofs_l[i] = cofs[blockIdx.x * (TILE * NREL) + i];
  __syncthreads();
  const int e0 = (int)cofs_l[0];
  const int etot = (int)cofs_l[320] - e0;
  const bool use_lds = (etot <= SPK_CAP);
  if (use_lds)
    for (int i = tid; i < etot; i += 512) spk[i] = es[e0 + i];
  __syncthreads();

  f32x4 acc = (f32x4){0.f, 0.f, 0.f, 0.f};

  for (int c = 0; c < 5; ++c) {
    // ---- phase 1: merged-range walk, packed-f16 accumulate, batch-4 ----
    if (c < 4) {
      const int cbase = g * NREL + c * 5;
      const int rlA = half ? 2 : 0;
      const int rlB = half ? 5 : 2;
      const int beg    = (int)cofs_l[cbase + rlA] - e0;
      const int endAll = (int)cofs_l[cbase + rlB] - e0;

      half8 a = (half8)(_Float16)0;
      int rl = rlA;
      int nend = (int)cofs_l[cbase + rl + 1] - e0;

      auto flush = [&]() {
        Sb8[g * 80 + ((rl * 16 + m) ^ g)] = a;   // already f16 = MFMA format
        a = (half8)(_Float16)0;
      };
      auto bump = [&](int i) {    // advance cell state past edge index i
        while (i >= nend) {
          flush();
          ++rl;
          nend = (int)cofs_l[cbase + rl + 1] - e0;
        }
      };
      auto run_walk = [&](auto fetch) {
        for (int i = beg; i < endAll; i += 4) {
          const int nrem = endAll - i;
          half8 h0, h1, h2, h3;
          h0 = fetch(i);
          if (nrem > 1) h1 = fetch(i + 1);
          if (nrem > 2) h2 = fetch(i + 2);
          if (nrem > 3) h3 = fetch(i + 3);
          bump(i);      a += h0;          // 4x v_pk_add_f16
          if (nrem > 1) { bump(i + 1); a += h1; }
          if (nrem > 2) { bump(i + 2); a += h2; }
          if (nrem > 3) { bump(i + 3); a += h3; }
        }
        while (rl < rlB) { flush(); ++rl; }   // trailing (incl. empty) cells
      };

      if (use_lds) {
        run_walk([&](int i) {
          return *(const half8*)(hb + (size_t)spk[i] * DIM + mh8);
        });
      } else {   // overflow fallback (essentially never taken)
        run_walk([&](int i) {
          return *(const half8*)(hb + (size_t)es[e0 + i] * DIM + mh8);
        });
      }
    } else if (half == 0) {
      // self-loop mini-chunk: own row (feeds rel 20 = loop_w), slot 0
      half8 hv = *(const half8*)(hb + (size_t)(dst_base + g) * DIM + mh8);
      Sb8[g * 80 + (m ^ g)] = hv;   // already f16; sum of one row
    }
    __syncthreads();

    // ---- phase 2: nc-split 8 ways. wave w owns cols [16w,16w+16) ----
    const int rc = (c == 4) ? 1 : 5;
    for (int rl2 = 0; rl2 < rc; ++rl2) {
      const int r = (c == 4) ? (NRELP - 1) : (c * 5 + rl2);
      const unsigned short* bp =
          WP + ((((size_t)(layer * NRELP + r) * 4) * 8 + w) * 64 + lane) * 8;
#pragma unroll
      for (int ks = 0; ks < 4; ++ks) {
        half8 av = Sb8[m * 80 + ((rl2 * 16 + ks * 4 + quad) ^ m)];
        half8 bv = *(const half8*)(bp + (size_t)ks * 4096);
        acc = __builtin_amdgcn_mfma_f32_16x16x32_f16(av, bv, acc, 0, 0, 0);
      }
    }
    __syncthreads();
  }

  // ---- epilogue: wave w stores its 16-col tile; no cross-wave reduction ----
  const int col = w * 16 + m;
  const float bv = bias[col];
  if (outb) {
#pragma unroll
    for (int i = 0; i < 4; ++i)
      outb[(size_t)(dst_base + quad * 4 + i) * DIM + col] =
          f32_to_f16_raw(acc[i] + bv);
  } else {
#pragma unroll
    for (int i = 0; i < 4; ++i)
      outf[(size_t)(dst_base + quad * 4 + i) * DIM + col] = acc[i] + bv;
  }
}

// ---------------- launch ----------------
extern "C" void kernel_launch(void* const* d_in, const int* in_sizes, int n_in,
                              void* d_out, int out_size, void* d_ws, size_t ws_size,
                              hipStream_t stream) {
  const float* h0     = (const float*)d_in[0];
  const float* W      = (const float*)d_in[1];
  const float* loop_w = (const float*)d_in[2];
  const float* bias   = (const float*)d_in[3];
  const int* esrc     = (const int*)d_in[4];
  const int* edst     = (const int*)d_in[5];
  const int* etyp     = (const int*)d_in[6];
  float* out = (float*)d_out;

  char* ws = (char*)d_ws;
  size_t off = 0;
  auto alloc = [&](size_t bytes) -> void* {
    void* p = ws + off;
    off = (off + bytes + 255) & ~(size_t)255;
    return p;
  };
  unsigned short* hb0   = (unsigned short*)alloc((size_t)NN * DIM * 2);   // 12.8 MB
  unsigned short* hb1   = (unsigned short*)alloc((size_t)NN * DIM * 2);   // 12.8 MB
  unsigned short* WP    = (unsigned short*)alloc((size_t)PACKED_ELEMS * 2);
  unsigned int*   cnt   = (unsigned int*)alloc((size_t)CHB * NTILE * 4);  // 3.2 MB
  unsigned int*   csum  = (unsigned int*)alloc((size_t)NTILE * 4);
  unsigned int*   starts= (unsigned int*)alloc((size_t)(NTILE + 1) * 4);
  unsigned int*   ep    = (unsigned int*)alloc((size_t)NE * 4);           // 6.4 MB
  unsigned int*   cofs  = (unsigned int*)alloc((size_t)(CELLS + 1) * 4);  // 4 MB
  unsigned short* es    = (unsigned short*)alloc((size_t)NE * 2);         // 3.2 MB

  cnt_kernel<<<CHB, 256, 0, stream>>>(edst, cnt);
  colscan_kernel<<<(NTILE + 255) / 256, 256, 0, stream>>>(cnt, csum);
  scan1_kernel<<<1, 1024, 0, stream>>>(csum, starts);
  scatter_kernel<<<CHB, 256, 0, stream>>>(esrc, edst, etyp, starts, cnt, ep);
  tile_sort_kernel<<<NTILE, 512, 0, stream>>>(ep, starts, es, cofs);

  pack_w_kernel<<<(PACKED_ELEMS + 255) / 256, 256, 0, stream>>>(W, loop_w, WP);
  cvt_f16_kernel<<<(NN * DIM / 4 + 255) / 256, 256, 0, stream>>>(h0, hb0, NN * DIM / 4);

  rgcn_layer_kernel<<<NTILE, 512, 0, stream>>>(hb0, WP, bias, 0, cofs, es,
                                               nullptr, hb1);
  rgcn_layer_kernel<<<NTILE, 512, 0, stream>>>(hb1, WP, bias + DIM, 1, cofs, es,
                                               out, nullptr);
}

// Round 11
// 381.885 us; speedup vs baseline: 1.0378x; 1.0378x over previous
//
#include <hip/hip_runtime.h>
#include <hip/hip_bf16.h>
#include <stdint.h>

// GNN_758: stacked RelGraphConv x2.  N=50000, E=1.6M, D=128, R=20.
// agg[dst] = sum_r (sum_{e in rel r -> dst} h[src]) @ W[r]; self-loop = rel 20.
// R18: two targeted fixes on the R17 base (layer internals otherwise frozen):
//  (1) colscan was 13 blocks on 256 CUs (pure latency, ~25us). Now wave-per-
//      bin: lane sums 4 chunk-blocks, __shfl_up wave-scan, 782 blocks.
//  (2) gather batch 4 -> 6 (24 VGPR in flight; VGPR was 32 of 64 cap).
//      R14's batch-8 spill signature to watch: WRITE_SIZE >> 12.5MB.

#define NN 50000
#define NE 1600000
#define DIM 128
#define NREL 20
#define NRELP 21
#define TILE 16
#define NTILE (NN / TILE)          // 3125 = tile bins
#define CELLS (NN * NREL)          // dst*20 + r
#define CHB 256                    // chunk blocks for count/scatter
#define CHE (NE / CHB)             // 6250 edges per chunk block
#define SPK_CAP 1024               // staged srcs per block (mean 512, sd ~23)
#define PACKED_ELEMS (2 * NRELP * 4 * 8 * 64 * 8)    // 688128

typedef __attribute__((ext_vector_type(8))) short short8;
typedef __attribute__((ext_vector_type(8))) _Float16 half8;
typedef __attribute__((ext_vector_type(4))) float f32x4;

__device__ __forceinline__ unsigned short f32_to_f16_raw(float f) {
  union { _Float16 h; unsigned short u; } c;
  c.h = (_Float16)f;               // v_cvt_f16_f32 (RNE)
  return c.u;
}

// ---------------- fp32 -> f16 (x4), nontemporal stores ----------------
__global__ void cvt_f16_kernel(const float* __restrict__ in,
                               unsigned short* __restrict__ out, int n4) {
  int i = blockIdx.x * 256 + threadIdx.x;
  if (i < n4) {
    float4 f = ((const float4*)in)[i];
    unsigned long long p =
        (unsigned long long)f32_to_f16_raw(f.x)
      | ((unsigned long long)f32_to_f16_raw(f.y) << 16)
      | ((unsigned long long)f32_to_f16_raw(f.z) << 32)
      | ((unsigned long long)f32_to_f16_raw(f.w) << 48);
    __builtin_nontemporal_store(p, (unsigned long long*)out + i);  // clean -> L3
  }
}

// ---------------- pack W (+loop_w as rel 20) into B-fragment order ----------------
// WP flat: ((((l*21 + r)*4 + ks)*8 + nc)*64 + lane)*8  (verified R0/R1), f16
__global__ void pack_w_kernel(const float* __restrict__ W,
                              const float* __restrict__ loop_w,
                              unsigned short* __restrict__ WP) {
  int idx = blockIdx.x * 256 + threadIdx.x;
  if (idx >= PACKED_ELEMS) return;
  int j = idx & 7;       int t = idx >> 3;
  int lane = t & 63;     t >>= 6;
  int nc = t & 7;        t >>= 3;
  int ks = t & 3;        t >>= 2;
  int r = t % NRELP;     int l = t / NRELP;
  int k = ks * 32 + (lane >> 4) * 8 + j;
  int n = nc * 16 + (lane & 15);
  float v = (r < NREL) ? W[(((size_t)l * NREL + r) * DIM + k) * DIM + n]
                       : loop_w[((size_t)l * DIM + k) * DIM + n];
  WP[idx] = f32_to_f16_raw(v);
}

// ---------------- tile counting sort, all global accesses coalesced ----------------
// bin = dst>>4 (3125 bins).  cnt layout: [blk][NTILE] rows (coalesced).
__global__ __launch_bounds__(256) void cnt_kernel(
    const int* __restrict__ dst, unsigned int* __restrict__ cnt) {
  __shared__ unsigned int h[NTILE];              // 12.5 KB
  for (int i = threadIdx.x; i < NTILE; i += 256) h[i] = 0u;
  __syncthreads();
  const int base = blockIdx.x * CHE;
  for (int i = base + threadIdx.x; i < base + CHE; i += 256)
    atomicAdd(&h[dst[i] >> 4], 1u);              // LDS atomic
  __syncthreads();
  unsigned int* row = cnt + (size_t)blockIdx.x * NTILE;
  for (int i = threadIdx.x; i < NTILE; i += 256) row[i] = h[i];
}

// wave-per-bin exclusive prefix over the 256 chunk-blocks (in place) + totals.
// lane handles blks [lane*4, lane*4+4); __shfl_up wave-scan combines lanes.
__global__ __launch_bounds__(256) void colscan_kernel(
    unsigned int* __restrict__ cnt, unsigned int* __restrict__ csum) {
  const int b = (blockIdx.x * 256 + threadIdx.x) >> 6;   // bin = wave id
  const int lane = threadIdx.x & 63;
  if (b >= NTILE) return;
  unsigned int v[4], p[4], s = 0;
#pragma unroll
  for (int i = 0; i < 4; ++i) {
    v[i] = cnt[(size_t)(lane * 4 + i) * NTILE + b];
    p[i] = s; s += v[i];
  }
  unsigned int run = s;
  for (int d = 1; d < 64; d <<= 1) {
    unsigned int t = __shfl_up(run, d);
    if (lane >= d) run += t;
  }
  const unsigned int excl = run - s;     // exclusive prefix of this lane
#pragma unroll
  for (int i = 0; i < 4; ++i)
    cnt[(size_t)(lane * 4 + i) * NTILE + b] = excl + p[i];
  if (lane == 63) csum[b] = run;         // bin total
}

// single-block exclusive scan of csum[NTILE] -> starts[NTILE+1] (sentinel=NE)
__global__ __launch_bounds__(1024) void scan1_kernel(
    const unsigned int* __restrict__ csum, unsigned int* __restrict__ starts) {
  __shared__ unsigned int buf[1024];
  const int t = threadIdx.x;
  const int base = t * 4;
  unsigned int v[4], p[4], s = 0;
#pragma unroll
  for (int j = 0; j < 4; ++j) {
    v[j] = (base + j < NTILE) ? csum[base + j] : 0u;
    p[j] = s; s += v[j];
  }
  buf[t] = s;
  __syncthreads();
  for (int d = 1; d < 1024; d <<= 1) {
    unsigned int a = (t >= d) ? buf[t - d] : 0u;
    __syncthreads();
    buf[t] += a;
    __syncthreads();
  }
  unsigned int excl = buf[t] - s;
#pragma unroll
  for (int j = 0; j < 4; ++j)
    if (base + j < NTILE) starts[base + j] = excl + p[j];
  if (t == 1023) starts[NTILE] = buf[1023];      // = NE
}

// scatter to tile-sorted position. payload = src | dd<<16 | rel<<20 (5 bits).
__global__ __launch_bounds__(256) void scatter_kernel(
    const int* __restrict__ src, const int* __restrict__ dst,
    const int* __restrict__ et, const unsigned int* __restrict__ starts,
    const unsigned int* __restrict__ cnt, unsigned int* __restrict__ ep) {
  __shared__ unsigned int cur[NTILE];            // 12.5 KB
  const unsigned int* row = cnt + (size_t)blockIdx.x * NTILE;
  for (int i = threadIdx.x; i < NTILE; i += 256)
    cur[i] = starts[i] + row[i];
  __syncthreads();
  const int base = blockIdx.x * CHE;
  for (int i = base + threadIdx.x; i < base + CHE; i += 256) {
    int d = dst[i];
    unsigned int pos = atomicAdd(&cur[d >> 4], 1u);   // LDS atomic
    ep[pos] = (unsigned int)src[i] | ((unsigned int)(d & 15) << 16)
            | ((unsigned int)et[i] << 20);
  }
}

// per-tile 320-bin sort -> cofs (dst*20+r layout) + es (u16 src). (= R15)
__global__ __launch_bounds__(512) void tile_sort_kernel(
    const unsigned int* __restrict__ ep, const unsigned int* __restrict__ starts,
    unsigned short* __restrict__ es, unsigned int* __restrict__ cofs) {
  __shared__ unsigned int hist[512];             // 320 bins, padded for scan
  const int t = threadIdx.x;
  const int tile = blockIdx.x;
  const unsigned int start = starts[tile];
  const unsigned int end = starts[tile + 1];
  const int cnt = (int)(end - start);
  hist[t] = 0u;
  __syncthreads();
  for (int i = t; i < cnt; i += 512) {
    unsigned int p = ep[start + i];
    atomicAdd(&hist[((p >> 16) & 15u) * 20u + (p >> 20)], 1u);
  }
  __syncthreads();
  unsigned int own = hist[t];
  for (int d = 1; d < 512; d <<= 1) {
    __syncthreads();
    unsigned int a = (t >= d) ? hist[t - d] : 0u;
    __syncthreads();
    hist[t] += a;
  }
  __syncthreads();
  unsigned int excl = hist[t] - own;     // exclusive prefix (own slot only)
  hist[t] = excl;                        // becomes rank cursor
  if (t < 320) cofs[(size_t)tile * 320 + t] = start + excl;
  if (tile == NTILE - 1 && t == 0) cofs[CELLS] = (unsigned int)NE;
  __syncthreads();
  for (int i = t; i < cnt; i += 512) {
    unsigned int p = ep[start + i];
    int sub = (int)(((p >> 16) & 15u) * 20u + (p >> 20));
    unsigned int rk = atomicAdd(&hist[sub], 1u);
    es[start + rk] = (unsigned short)(p & 0xffffu);
  }
}

// ---------------- fused RGCN layer (R15 + batch-6 gather) ----------------
// 3125 blocks x 512 threads (8 waves). LDS ~23.3KB -> 4 blocks/CU (wave cap).
__global__ __launch_bounds__(512, 8) void rgcn_layer_kernel(
    const unsigned short* __restrict__ hb,    // [N,128] f16
    const unsigned short* __restrict__ WP,    // packed weights, f16
    const float* __restrict__ bias,           // [128] this layer
    int layer,
    const unsigned int* __restrict__ cofs,    // [CELLS+1] cell offsets
    const unsigned short* __restrict__ es,    // [E] srcs, cell-sorted
    float* __restrict__ outf,                 // fp32 out (layer 1) or null
    unsigned short* __restrict__ outb)        // f16 out (layer 0) or null
{
  // Sb: [16 dst rows][5 rl slots * 16 slot16], slot16 = 8 f16 (16B),
  // slot index ^= (row & 15) -> conflict-free writes and reads (verified R8).
  __shared__ half8 Sb8[TILE * 80];           // 20480 B
  __shared__ unsigned int cofs_l[321];       // 1284 B
  __shared__ unsigned short spk[SPK_CAP];    // 2048 B

  const int tid  = threadIdx.x;
  const int lane = tid & 63;
  const int w    = tid >> 6;        // wave 0..7
  const int quad = lane >> 4;
  const int m    = lane & 15;
  const int mh8  = m * 8;
  const int half = w >> 2;          // 0: rl{0,1}  1: rl{2,3,4}  (wave-uniform)
  const int g    = (w & 3) * 4 + quad;   // owned dst_local 0..15
  const int dst_base = blockIdx.x * TILE;

  for (int i = tid; i < 321; i += 512) cofs_l[i] = cofs[blockIdx.x * (TILE * NREL) + i];
  __syncthreads();
  const int e0 = (int)cofs_l[0];
  const int etot = (int)cofs_l[320] - e0;
  const bool use_lds = (etot <= SPK_CAP);
  if (use_lds)
    for (int i = tid; i < etot; i += 512) spk[i] = es[e0 + i];
  __syncthreads();

  f32x4 acc = (f32x4){0.f, 0.f, 0.f, 0.f};

  for (int c = 0; c < 5; ++c) {
    // ---- phase 1: merged-range walk, packed-f16 accumulate, batch-6 ----
    if (c < 4) {
      const int cbase = g * NREL + c * 5;
      const int rlA = half ? 2 : 0;
      const int rlB = half ? 5 : 2;
      const int beg    = (int)cofs_l[cbase + rlA] - e0;
      const int endAll = (int)cofs_l[cbase + rlB] - e0;

      half8 a = (half8)(_Float16)0;
      int rl = rlA;
      int nend = (int)cofs_l[cbase + rl + 1] - e0;

      auto flush = [&]() {
        Sb8[g * 80 + ((rl * 16 + m) ^ g)] = a;   // already f16 = MFMA format
        a = (half8)(_Float16)0;
      };
      auto bump = [&](int i) {    // advance cell state past edge index i
        while (i >= nend) {
          flush();
          ++rl;
          nend = (int)cofs_l[cbase + rl + 1] - e0;
        }
      };
      auto run_walk = [&](auto fetch) {
        for (int i = beg; i < endAll; i += 6) {
          const int nrem = endAll - i;
          half8 h0, h1, h2, h3, h4, h5;
          h0 = fetch(i);
          if (nrem > 1) h1 = fetch(i + 1);
          if (nrem > 2) h2 = fetch(i + 2);
          if (nrem > 3) h3 = fetch(i + 3);
          if (nrem > 4) h4 = fetch(i + 4);
          if (nrem > 5) h5 = fetch(i + 5);
          bump(i);      a += h0;          // 4x v_pk_add_f16
          if (nrem > 1) { bump(i + 1); a += h1; }
          if (nrem > 2) { bump(i + 2); a += h2; }
          if (nrem > 3) { bump(i + 3); a += h3; }
          if (nrem > 4) { bump(i + 4); a += h4; }
          if (nrem > 5) { bump(i + 5); a += h5; }
        }
        while (rl < rlB) { flush(); ++rl; }   // trailing (incl. empty) cells
      };

      if (use_lds) {
        run_walk([&](int i) {
          return *(const half8*)(hb + (size_t)spk[i] * DIM + mh8);
        });
      } else {   // overflow fallback (essentially never taken)
        run_walk([&](int i) {
          return *(const half8*)(hb + (size_t)es[e0 + i] * DIM + mh8);
        });
      }
    } else if (half == 0) {
      // self-loop mini-chunk: own row (feeds rel 20 = loop_w), slot 0
      half8 hv = *(const half8*)(hb + (size_t)(dst_base + g) * DIM + mh8);
      Sb8[g * 80 + (m ^ g)] = hv;   // already f16; sum of one row
    }
    __syncthreads();

    // ---- phase 2: nc-split 8 ways. wave w owns cols [16w,16w+16) ----
    const int rc = (c == 4) ? 1 : 5;
    for (int rl2 = 0; rl2 < rc; ++rl2) {
      const int r = (c == 4) ? (NRELP - 1) : (c * 5 + rl2);
      const unsigned short* bp =
          WP + ((((size_t)(layer * NRELP + r) * 4) * 8 + w) * 64 + lane) * 8;
#pragma unroll
      for (int ks = 0; ks < 4; ++ks) {
        half8 av = Sb8[m * 80 + ((rl2 * 16 + ks * 4 + quad) ^ m)];
        half8 bv = *(const half8*)(bp + (size_t)ks * 4096);
        acc = __builtin_amdgcn_mfma_f32_16x16x32_f16(av, bv, acc, 0, 0, 0);
      }
    }
    __syncthreads();
  }

  // ---- epilogue: wave w stores its 16-col tile; no cross-wave reduction ----
  const int col = w * 16 + m;
  const float bv = bias[col];
  if (outb) {
#pragma unroll
    for (int i = 0; i < 4; ++i)
      outb[(size_t)(dst_base + quad * 4 + i) * DIM + col] =
          f32_to_f16_raw(acc[i] + bv);
  } else {
#pragma unroll
    for (int i = 0; i < 4; ++i)
      outf[(size_t)(dst_base + quad * 4 + i) * DIM + col] = acc[i] + bv;
  }
}

// ---------------- launch ----------------
extern "C" void kernel_launch(void* const* d_in, const int* in_sizes, int n_in,
                              void* d_out, int out_size, void* d_ws, size_t ws_size,
                              hipStream_t stream) {
  const float* h0     = (const float*)d_in[0];
  const float* W      = (const float*)d_in[1];
  const float* loop_w = (const float*)d_in[2];
  const float* bias   = (const float*)d_in[3];
  const int* esrc     = (const int*)d_in[4];
  const int* edst     = (const int*)d_in[5];
  const int* etyp     = (const int*)d_in[6];
  float* out = (float*)d_out;

  char* ws = (char*)d_ws;
  size_t off = 0;
  auto alloc = [&](size_t bytes) -> void* {
    void* p = ws + off;
    off = (off + bytes + 255) & ~(size_t)255;
    return p;
  };
  unsigned short* hb0   = (unsigned short*)alloc((size_t)NN * DIM * 2);   // 12.8 MB
  unsigned short* hb1   = (unsigned short*)alloc((size_t)NN * DIM * 2);   // 12.8 MB
  unsigned short* WP    = (unsigned short*)alloc((size_t)PACKED_ELEMS * 2);
  unsigned int*   cnt   = (unsigned int*)alloc((size_t)CHB * NTILE * 4);  // 3.2 MB
  unsigned int*   csum  = (unsigned int*)alloc((size_t)NTILE * 4);
  unsigned int*   starts= (unsigned int*)alloc((size_t)(NTILE + 1) * 4);
  unsigned int*   ep    = (unsigned int*)alloc((size_t)NE * 4);           // 6.4 MB
  unsigned int*   cofs  = (unsigned int*)alloc((size_t)(CELLS + 1) * 4);  // 4 MB
  unsigned short* es    = (unsigned short*)alloc((size_t)NE * 2);         // 3.2 MB

  cnt_kernel<<<CHB, 256, 0, stream>>>(edst, cnt);
  colscan_kernel<<<(NTILE * 64 + 255) / 256, 256, 0, stream>>>(cnt, csum);
  scan1_kernel<<<1, 1024, 0, stream>>>(csum, starts);
  scatter_kernel<<<CHB, 256, 0, stream>>>(esrc, edst, etyp, starts, cnt, ep);
  tile_sort_kernel<<<NTILE, 512, 0, stream>>>(ep, starts, es, cofs);

  pack_w_kernel<<<(PACKED_ELEMS + 255) / 256, 256, 0, stream>>>(W, loop_w, WP);
  cvt_f16_kernel<<<(NN * DIM / 4 + 255) / 256, 256, 0, stream>>>(h0, hb0, NN * DIM / 4);

  rgcn_layer_kernel<<<NTILE, 512, 0, stream>>>(hb0, WP, bias, 0, cofs, es,
                                               nullptr, hb1);
  rgcn_layer_kernel<<<NTILE, 512, 0, stream>>>(hb1, WP, bias + DIM, 1, cofs, es,
                                               out, nullptr);
}